// Round 3
// baseline (589.835 us; speedup 1.0000x reference)
//
#include <hip/hip_runtime.h>
#include <hip/hip_bf16.h>

// CapsuleLayer dynamic routing — register-resident u_hat, barrier-minimal.
// B=512, R=1152, C=10, O=16, I=8, 3 routing iters.
// Lane mapping: rr = t>>4 (route in chunk), o = t&15 (out channel).
// u[bt][c] in registers IS the fragment for both agreement
// (reduce over o = 16-lane xor butterfly) and s-accumulation
// (reduce over rr = xor16/32 + 4-wave LDS reduce).
// ws layout (floats): s[81920] | v[81920] | b_ij[512*1152*10]

#define BB   512
#define RR   1152
#define CC   10
#define OO   16
#define II   8
#define CO   160
#define BT   4
#define RT   16
#define NB_B (BB/BT)  // 128
#define NB_R (RR/RT)  // 72

template <int K>
__global__ __launch_bounds__(256, 4) void route_pass(
    const float* __restrict__ x, const float* __restrict__ W,
    const float* __restrict__ v_in, float* __restrict__ b_ij,
    float* __restrict__ s_out)
{
    __shared__ float v_lds[BT * CO];      // 2.5 KB
    __shared__ float part[4 * BT * CO];   // 10 KB (wave, bt, co)

    const int t  = threadIdx.x;
    const int bb = blockIdx.x % NB_B;
    const int rc = blockIdx.x / NB_B;
    const int b0 = bb * BT;
    const int r0 = rc * RT;
    const int rr = t >> 4;    // 0..15
    const int o  = t & 15;    // 0..15
    const int wv = t >> 6;    // 0..3

    if (K > 0) {
        for (int i = t; i < BT * CO; i += 256)
            v_lds[i] = v_in[(size_t)b0 * CO + i];
    }

    // ---- x into registers (16-lane broadcast per row) ----
    float xr[BT][II];
    #pragma unroll
    for (int bt = 0; bt < BT; ++bt) {
        const float4* xp = reinterpret_cast<const float4*>(
            x + ((size_t)(b0 + bt) * RR + (r0 + rr)) * II);
        float4 x0 = xp[0], x1 = xp[1];
        xr[bt][0] = x0.x; xr[bt][1] = x0.y; xr[bt][2] = x0.z; xr[bt][3] = x0.w;
        xr[bt][4] = x1.x; xr[bt][5] = x1.y; xr[bt][6] = x1.z; xr[bt][7] = x1.w;
    }

    // ---- Phase A: u[bt][c] = u_hat[b0+bt][r0+rr][c][o] ----
    float u[BT][CC];
    #pragma unroll
    for (int c = 0; c < CC; ++c) {
        const float4* wp = reinterpret_cast<const float4*>(
            W + ((size_t)(r0 + rr) * CO + c * 16 + o) * II);
        float4 w0 = wp[0], w1 = wp[1];
        #pragma unroll
        for (int bt = 0; bt < BT; ++bt) {
            u[bt][c] = w0.x * xr[bt][0] + w0.y * xr[bt][1] + w0.z * xr[bt][2] + w0.w * xr[bt][3]
                     + w1.x * xr[bt][4] + w1.y * xr[bt][5] + w1.z * xr[bt][6] + w1.w * xr[bt][7];
        }
    }

    __syncthreads();   // v_lds visible

    // ---- Phase B: agreement + b_ij + softmax, fully in registers ----
    float cw[BT][CC];
    if (K > 0) {
        #pragma unroll
        for (int bt = 0; bt < BT; ++bt) {
            float a[CC];
            #pragma unroll
            for (int c = 0; c < CC; ++c) {
                float p = u[bt][c] * v_lds[bt * CO + c * 16 + o];
                p += __shfl_xor(p, 1);
                p += __shfl_xor(p, 2);
                p += __shfl_xor(p, 4);
                p += __shfl_xor(p, 8);
                a[c] = p;          // broadcast to all 16 lanes of this rr-group
            }
            const size_t gbase = ((size_t)(b0 + bt) * RR + (r0 + rr)) * CC;
            if (K == 2) {
                #pragma unroll
                for (int c = 0; c < CC; ++c) a[c] += b_ij[gbase + c];  // 16-lane broadcast loads
            } else {
                #pragma unroll
                for (int c = 0; c < CC; ++c)
                    if (o == c) b_ij[gbase + c] = a[c];   // one lane per c stores
            }
            float m = a[0];
            #pragma unroll
            for (int c = 1; c < CC; ++c) m = fmaxf(m, a[c]);
            float ssum = 0.0f;
            #pragma unroll
            for (int c = 0; c < CC; ++c) { a[c] = __expf(a[c] - m); ssum += a[c]; }
            float inv = 1.0f / ssum;
            #pragma unroll
            for (int c = 0; c < CC; ++c) cw[bt][c] = a[c] * inv;
        }
    }

    // ---- Phase C: reduce c_ij*u over rr ----
    #pragma unroll
    for (int bt = 0; bt < BT; ++bt) {
        #pragma unroll
        for (int c = 0; c < CC; ++c) {
            float q = (K == 0 ? 0.1f : cw[bt][c]) * u[bt][c];
            q += __shfl_xor(q, 16);
            q += __shfl_xor(q, 32);     // sum over this wave's 4 rr
            if ((t & 63) < 16)
                part[(wv * BT + bt) * CO + c * 16 + o] = q;
        }
    }
    __syncthreads();
    for (int i = t; i < BT * CO; i += 256) {
        float acc = part[i] + part[BT * CO + i] + part[2 * BT * CO + i] + part[3 * BT * CO + i];
        atomicAdd(&s_out[(size_t)b0 * CO + i], acc);
    }
}

__global__ __launch_bounds__(256) void squash_kernel(
    const float* __restrict__ s, const float* __restrict__ bias,
    float* __restrict__ v_out)
{
    const int idx = blockIdx.x * 256 + threadIdx.x;   // < 81920
    const int co = idx % CO;
    float sv = s[idx] + bias[co];
    float n2 = sv * sv;
    n2 += __shfl_xor(n2, 1);
    n2 += __shfl_xor(n2, 2);
    n2 += __shfl_xor(n2, 4);
    n2 += __shfl_xor(n2, 8);
    float norm = sqrtf(n2);
    float scale = norm / (1.0f + n2 + 1e-8f);
    v_out[idx] = scale * sv;
}

extern "C" void kernel_launch(void* const* d_in, const int* in_sizes, int n_in,
                              void* d_out, int out_size, void* d_ws, size_t ws_size,
                              hipStream_t stream) {
    const float* x    = (const float*)d_in[0];
    const float* W    = (const float*)d_in[1];
    const float* bias = (const float*)d_in[2];
    float* out = (float*)d_out;

    float* s   = (float*)d_ws;          // 81920 floats
    float* v   = s + BB * CO;           // 81920 floats
    float* bij = v + BB * CO;           // 512*1152*10 floats

    const dim3 blk(256);
    const dim3 rgrid(NB_B * NB_R);      // 9216

    hipMemsetAsync(s, 0, (size_t)BB * CO * sizeof(float), stream);
    route_pass<0><<<rgrid, blk, 0, stream>>>(x, W, v, bij, s);
    squash_kernel<<<320, blk, 0, stream>>>(s, bias, v);

    hipMemsetAsync(s, 0, (size_t)BB * CO * sizeof(float), stream);
    route_pass<1><<<rgrid, blk, 0, stream>>>(x, W, v, bij, s);
    squash_kernel<<<320, blk, 0, stream>>>(s, bias, v);

    hipMemsetAsync(s, 0, (size_t)BB * CO * sizeof(float), stream);
    route_pass<2><<<rgrid, blk, 0, stream>>>(x, W, v, bij, s);
    squash_kernel<<<320, blk, 0, stream>>>(s, bias, out);
}

// Round 4
// 493.897 us; speedup vs baseline: 1.1942x; 1.1942x over previous
//
#include <hip/hip_runtime.h>
#include <hip/hip_bf16.h>

// CapsuleLayer dynamic routing — register-resident u_hat, spill-free variant.
// B=512, R=1152, C=10, O=16, I=8, 3 routing iters.
// Lane mapping: rr = t>>4 (route in chunk), o = t&15 (out channel).
// Key change vs R3: phases B and C are FUSED per-bt so the softmax coeffs
// never persist across the bt loop (cw[4][10] -> a[10] in-place). Peak live
// registers ~80 < 128 cap -> no scratch spill (R3 spilled 850 MB/dispatch).
// ws layout (floats): s[81920] | v[81920] | b_ij[512*1152*10]

#define BB   512
#define RR   1152
#define CC   10
#define OO   16
#define II   8
#define CO   160
#define BT   4
#define RT   16
#define NB_B (BB/BT)  // 128
#define NB_R (RR/RT)  // 72

template <int K>
__global__ __launch_bounds__(256, 4) void route_pass(
    const float* __restrict__ x, const float* __restrict__ W,
    const float* __restrict__ v_in, float* __restrict__ b_ij,
    float* __restrict__ s_out)
{
    __shared__ float v_lds[BT * CO];      // 2.5 KB
    __shared__ float part[4 * BT * CO];   // 10 KB (wave, bt, co)

    const int t  = threadIdx.x;
    const int bb = blockIdx.x % NB_B;
    const int rc = blockIdx.x / NB_B;
    const int b0 = bb * BT;
    const int r0 = rc * RT;
    const int rr = t >> 4;    // 0..15
    const int o  = t & 15;    // 0..15
    const int wv = t >> 6;    // 0..3

    if (K > 0) {
        for (int i = t; i < BT * CO; i += 256)
            v_lds[i] = v_in[(size_t)b0 * CO + i];
    }

    // ---- Phase A: u[bt][c] = u_hat[b0+bt][r0+rr][c][o]; xr dead after ----
    float u[BT][CC];
    {
        float xr[BT][II];
        #pragma unroll
        for (int bt = 0; bt < BT; ++bt) {
            const float4* xp = reinterpret_cast<const float4*>(
                x + ((size_t)(b0 + bt) * RR + (r0 + rr)) * II);
            float4 x0 = xp[0], x1 = xp[1];
            xr[bt][0] = x0.x; xr[bt][1] = x0.y; xr[bt][2] = x0.z; xr[bt][3] = x0.w;
            xr[bt][4] = x1.x; xr[bt][5] = x1.y; xr[bt][6] = x1.z; xr[bt][7] = x1.w;
        }
        #pragma unroll
        for (int c = 0; c < CC; ++c) {
            const float4* wp = reinterpret_cast<const float4*>(
                W + ((size_t)(r0 + rr) * CO + c * 16 + o) * II);
            float4 w0 = wp[0], w1 = wp[1];
            #pragma unroll
            for (int bt = 0; bt < BT; ++bt) {
                u[bt][c] = w0.x * xr[bt][0] + w0.y * xr[bt][1] + w0.z * xr[bt][2] + w0.w * xr[bt][3]
                         + w1.x * xr[bt][4] + w1.y * xr[bt][5] + w1.z * xr[bt][6] + w1.w * xr[bt][7];
            }
        }
    }

    __syncthreads();   // v_lds visible

    // ---- Phases B+C fused per bt: agreement -> softmax -> weighted reduce ----
    #pragma unroll
    for (int bt = 0; bt < BT; ++bt) {
        float a[CC];
        if (K > 0) {
            #pragma unroll
            for (int c = 0; c < CC; ++c) {
                float p = u[bt][c] * v_lds[bt * CO + c * 16 + o];
                p += __shfl_xor(p, 1);
                p += __shfl_xor(p, 2);
                p += __shfl_xor(p, 4);
                p += __shfl_xor(p, 8);
                a[c] = p;          // broadcast across the 16 lanes of this rr
            }
            const size_t gbase = ((size_t)(b0 + bt) * RR + (r0 + rr)) * CC;
            if (K == 2) {
                #pragma unroll
                for (int c = 0; c < CC; ++c) a[c] += b_ij[gbase + c];
            } else {
                #pragma unroll
                for (int c = 0; c < CC; ++c)
                    if (o == c) b_ij[gbase + c] = a[c];   // one lane per c
            }
            float m = a[0];
            #pragma unroll
            for (int c = 1; c < CC; ++c) m = fmaxf(m, a[c]);
            float ssum = 0.0f;
            #pragma unroll
            for (int c = 0; c < CC; ++c) { a[c] = __expf(a[c] - m); ssum += a[c]; }
            float inv = 1.0f / ssum;
            #pragma unroll
            for (int c = 0; c < CC; ++c) a[c] *= inv;     // a[] now holds c_ij
        }
        #pragma unroll
        for (int c = 0; c < CC; ++c) {
            float q = (K == 0 ? 0.1f : a[c]) * u[bt][c];
            q += __shfl_xor(q, 16);
            q += __shfl_xor(q, 32);     // sum over this wave's 4 rr
            if ((t & 63) < 16)
                part[(wv * BT + bt) * CO + c * 16 + o] = q;
        }
    }
    __syncthreads();
    for (int i = t; i < BT * CO; i += 256) {
        float acc = part[i] + part[BT * CO + i] + part[2 * BT * CO + i] + part[3 * BT * CO + i];
        atomicAdd(&s_out[(size_t)b0 * CO + i], acc);
    }
}

__global__ __launch_bounds__(256) void squash_kernel(
    const float* __restrict__ s, const float* __restrict__ bias,
    float* __restrict__ v_out)
{
    const int idx = blockIdx.x * 256 + threadIdx.x;   // < 81920
    const int co = idx % CO;
    float sv = s[idx] + bias[co];
    float n2 = sv * sv;
    n2 += __shfl_xor(n2, 1);
    n2 += __shfl_xor(n2, 2);
    n2 += __shfl_xor(n2, 4);
    n2 += __shfl_xor(n2, 8);
    float norm = sqrtf(n2);
    float scale = norm / (1.0f + n2 + 1e-8f);
    v_out[idx] = scale * sv;
}

extern "C" void kernel_launch(void* const* d_in, const int* in_sizes, int n_in,
                              void* d_out, int out_size, void* d_ws, size_t ws_size,
                              hipStream_t stream) {
    const float* x    = (const float*)d_in[0];
    const float* W    = (const float*)d_in[1];
    const float* bias = (const float*)d_in[2];
    float* out = (float*)d_out;

    float* s   = (float*)d_ws;          // 81920 floats
    float* v   = s + BB * CO;           // 81920 floats
    float* bij = v + BB * CO;           // 512*1152*10 floats

    const dim3 blk(256);
    const dim3 rgrid(NB_B * NB_R);      // 9216

    hipMemsetAsync(s, 0, (size_t)BB * CO * sizeof(float), stream);
    route_pass<0><<<rgrid, blk, 0, stream>>>(x, W, v, bij, s);
    squash_kernel<<<320, blk, 0, stream>>>(s, bias, v);

    hipMemsetAsync(s, 0, (size_t)BB * CO * sizeof(float), stream);
    route_pass<1><<<rgrid, blk, 0, stream>>>(x, W, v, bij, s);
    squash_kernel<<<320, blk, 0, stream>>>(s, bias, v);

    hipMemsetAsync(s, 0, (size_t)BB * CO * sizeof(float), stream);
    route_pass<2><<<rgrid, blk, 0, stream>>>(x, W, v, bij, s);
    squash_kernel<<<320, blk, 0, stream>>>(s, bias, out);
}

// Round 5
// 408.811 us; speedup vs baseline: 1.4428x; 1.2081x over previous
//
#include <hip/hip_runtime.h>
#include <hip/hip_bf16.h>

// CapsuleLayer dynamic routing — register-resident u_hat, spill-free variant.
// B=512, R=1152, C=10, O=16, I=8, 3 routing iters.
// Lane mapping: rr = t>>4 (route in chunk), o = t&15 (out channel).
// R4 lesson: __launch_bounds__(256,4) made the backend clamp to 64 VGPRs and
// spill u[4][10] (~210 MB scratch writes/dispatch). Plain (256) lets the
// allocator take the ~90-110 VGPRs the live set needs (still ~5 waves/SIMD).
// ws layout (floats): s[81920] | v[81920] | b_ij[512*1152*10]

#define BB   512
#define RR   1152
#define CC   10
#define OO   16
#define II   8
#define CO   160
#define BT   4
#define RT   16
#define NB_B (BB/BT)  // 128
#define NB_R (RR/RT)  // 72

template <int K>
__global__ __launch_bounds__(256) void route_pass(
    const float* __restrict__ x, const float* __restrict__ W,
    const float* __restrict__ v_in, float* __restrict__ b_ij,
    float* __restrict__ s_out)
{
    __shared__ float v_lds[BT * CO];      // 2.5 KB
    __shared__ float part[4 * BT * CO];   // 10 KB (wave, bt, co)

    const int t  = threadIdx.x;
    const int bb = blockIdx.x % NB_B;
    const int rc = blockIdx.x / NB_B;
    const int b0 = bb * BT;
    const int r0 = rc * RT;
    const int rr = t >> 4;    // 0..15
    const int o  = t & 15;    // 0..15
    const int wv = t >> 6;    // 0..3

    if (K > 0) {
        for (int i = t; i < BT * CO; i += 256)
            v_lds[i] = v_in[(size_t)b0 * CO + i];
    }

    // ---- Phase A: u[bt][c] = u_hat[b0+bt][r0+rr][c][o]; xr dead after ----
    float u[BT][CC];
    {
        float xr[BT][II];
        #pragma unroll
        for (int bt = 0; bt < BT; ++bt) {
            const float4* xp = reinterpret_cast<const float4*>(
                x + ((size_t)(b0 + bt) * RR + (r0 + rr)) * II);
            float4 x0 = xp[0], x1 = xp[1];
            xr[bt][0] = x0.x; xr[bt][1] = x0.y; xr[bt][2] = x0.z; xr[bt][3] = x0.w;
            xr[bt][4] = x1.x; xr[bt][5] = x1.y; xr[bt][6] = x1.z; xr[bt][7] = x1.w;
        }
        #pragma unroll
        for (int c = 0; c < CC; ++c) {
            const float4* wp = reinterpret_cast<const float4*>(
                W + ((size_t)(r0 + rr) * CO + c * 16 + o) * II);
            float4 w0 = wp[0], w1 = wp[1];
            #pragma unroll
            for (int bt = 0; bt < BT; ++bt) {
                u[bt][c] = w0.x * xr[bt][0] + w0.y * xr[bt][1] + w0.z * xr[bt][2] + w0.w * xr[bt][3]
                         + w1.x * xr[bt][4] + w1.y * xr[bt][5] + w1.z * xr[bt][6] + w1.w * xr[bt][7];
            }
        }
    }

    __syncthreads();   // v_lds visible

    // ---- Phases B+C fused per bt: agreement -> softmax -> weighted reduce ----
    #pragma unroll
    for (int bt = 0; bt < BT; ++bt) {
        float a[CC];
        if (K > 0) {
            #pragma unroll
            for (int c = 0; c < CC; ++c) {
                float p = u[bt][c] * v_lds[bt * CO + c * 16 + o];
                p += __shfl_xor(p, 1);
                p += __shfl_xor(p, 2);
                p += __shfl_xor(p, 4);
                p += __shfl_xor(p, 8);
                a[c] = p;          // broadcast across the 16 lanes of this rr
            }
            const size_t gbase = ((size_t)(b0 + bt) * RR + (r0 + rr)) * CC;
            if (K == 2) {
                #pragma unroll
                for (int c = 0; c < CC; ++c) a[c] += b_ij[gbase + c];
            } else {
                #pragma unroll
                for (int c = 0; c < CC; ++c)
                    if (o == c) b_ij[gbase + c] = a[c];   // one lane per c
            }
            float m = a[0];
            #pragma unroll
            for (int c = 1; c < CC; ++c) m = fmaxf(m, a[c]);
            float ssum = 0.0f;
            #pragma unroll
            for (int c = 0; c < CC; ++c) { a[c] = __expf(a[c] - m); ssum += a[c]; }
            float inv = 1.0f / ssum;
            #pragma unroll
            for (int c = 0; c < CC; ++c) a[c] *= inv;     // a[] now holds c_ij
        }
        #pragma unroll
        for (int c = 0; c < CC; ++c) {
            float q = (K == 0 ? 0.1f : a[c]) * u[bt][c];
            q += __shfl_xor(q, 16);
            q += __shfl_xor(q, 32);     // sum over this wave's 4 rr
            if ((t & 63) < 16)
                part[(wv * BT + bt) * CO + c * 16 + o] = q;
        }
    }
    __syncthreads();
    for (int i = t; i < BT * CO; i += 256) {
        float acc = part[i] + part[BT * CO + i] + part[2 * BT * CO + i] + part[3 * BT * CO + i];
        atomicAdd(&s_out[(size_t)b0 * CO + i], acc);
    }
}

__global__ __launch_bounds__(256) void squash_kernel(
    const float* __restrict__ s, const float* __restrict__ bias,
    float* __restrict__ v_out)
{
    const int idx = blockIdx.x * 256 + threadIdx.x;   // < 81920
    const int co = idx % CO;
    float sv = s[idx] + bias[co];
    float n2 = sv * sv;
    n2 += __shfl_xor(n2, 1);
    n2 += __shfl_xor(n2, 2);
    n2 += __shfl_xor(n2, 4);
    n2 += __shfl_xor(n2, 8);
    float norm = sqrtf(n2);
    float scale = norm / (1.0f + n2 + 1e-8f);
    v_out[idx] = scale * sv;
}

extern "C" void kernel_launch(void* const* d_in, const int* in_sizes, int n_in,
                              void* d_out, int out_size, void* d_ws, size_t ws_size,
                              hipStream_t stream) {
    const float* x    = (const float*)d_in[0];
    const float* W    = (const float*)d_in[1];
    const float* bias = (const float*)d_in[2];
    float* out = (float*)d_out;

    float* s   = (float*)d_ws;          // 81920 floats
    float* v   = s + BB * CO;           // 81920 floats
    float* bij = v + BB * CO;           // 512*1152*10 floats

    const dim3 blk(256);
    const dim3 rgrid(NB_B * NB_R);      // 9216

    hipMemsetAsync(s, 0, (size_t)BB * CO * sizeof(float), stream);
    route_pass<0><<<rgrid, blk, 0, stream>>>(x, W, v, bij, s);
    squash_kernel<<<320, blk, 0, stream>>>(s, bias, v);

    hipMemsetAsync(s, 0, (size_t)BB * CO * sizeof(float), stream);
    route_pass<1><<<rgrid, blk, 0, stream>>>(x, W, v, bij, s);
    squash_kernel<<<320, blk, 0, stream>>>(s, bias, v);

    hipMemsetAsync(s, 0, (size_t)BB * CO * sizeof(float), stream);
    route_pass<2><<<rgrid, blk, 0, stream>>>(x, W, v, bij, s);
    squash_kernel<<<320, blk, 0, stream>>>(s, bias, out);
}

// Round 7
// 397.330 us; speedup vs baseline: 1.4845x; 1.0289x over previous
//
#include <hip/hip_runtime.h>
#include <hip/hip_bf16.h>
#include <stdint.h>

// CapsuleLayer dynamic routing via bf16 MFMA (16x16x32), f32 routing math.
// B=512, R=1152, C=10, O=16, I=8, 3 iters.
// Pass0: s0 = 0.1*sum_r u_hat  == GEMM [co x (r,i)=9216] x [(r,i) x b] -> gemm0.
// Pass1/2: per-r MFMA tile u[16co x 16b]; D-layout (m89-verified):
//   lane l holds b = l&15, co_sub = (l>>4)*4 + reg  -> agreement over o is
//   4 FMA + shfl_xor(16) + shfl_xor(32); softmax in-register; s-acc in regs.
// A/B frags: lane l slot j ~ k=(l>>4)*8+j; K=8 real (i), rest zeros. Safe under
// any hw k-permutation (same convention both operands).
// ws (floats): v[81920] | s0[81920] | P[32*24*2560] | bij bf16[1152*10*512]

#define BB 512
#define RR 1152
#define CCAP 10
#define OO 16
#define II 8
#define CO 160
#define NBT 32
#define NSPLIT 24
#define RCHUNK 48   // r per block (24*48=1152)
#define RWAVE 12    // r per wave

typedef __attribute__((ext_vector_type(8))) short bf16x8;
typedef __attribute__((ext_vector_type(4))) float f32x4;

__device__ inline short f2bf(float f) {
    uint32_t b = __float_as_uint(f);
    uint32_t r = (b + 0x7FFFu + ((b >> 16) & 1u)) >> 16;
    return (short)r;
}
__device__ inline float bf2f(unsigned short u) {
    return __uint_as_float(((uint32_t)u) << 16);
}

// ---------------- pass 0: s0 = 0.1 * sum_{r,i} W[r,co,i] x[b,r,i] ----------
__global__ __launch_bounds__(256) void gemm0(
    const float* __restrict__ x, const float* __restrict__ W,
    float* __restrict__ s0)
{
    __shared__ float part[4 * 272];
    const int t = threadIdx.x;
    const int cot  = blockIdx.x % 10;
    const int bt   = (blockIdx.x / 10) % 32;
    const int half = blockIdx.x / 320;      // 0..1 (k-split)
    const int w = t >> 6, l = t & 63, lg = l >> 4, ln = l & 15;

    f32x4 acc; acc[0]=0.f; acc[1]=0.f; acc[2]=0.f; acc[3]=0.f;
    const int kt0 = half * 144 + w * 36;    // 288 k-tiles of K=32 total
    for (int q = 0; q < 36; ++q) {
        const int kt = kt0 + q;
        const int r  = kt * 4 + lg;         // k=(lg)*8+j -> r=kt*4+lg, i=j
        const float* ap = W + ((size_t)r * CO + cot * 16 + ln) * II;
        const float* bp = x + ((size_t)(bt * 16 + ln) * RR + r) * II;
        f32x4 a0 = *reinterpret_cast<const f32x4*>(ap);
        f32x4 a1 = *reinterpret_cast<const f32x4*>(ap + 4);
        f32x4 b0 = *reinterpret_cast<const f32x4*>(bp);
        f32x4 b1 = *reinterpret_cast<const f32x4*>(bp + 4);
        bf16x8 af, bf;
        #pragma unroll
        for (int j = 0; j < 4; ++j) {
            af[j] = f2bf(a0[j]); af[4+j] = f2bf(a1[j]);
            bf[j] = f2bf(b0[j]); bf[4+j] = f2bf(b1[j]);
        }
        acc = __builtin_amdgcn_mfma_f32_16x16x32_bf16(af, bf, acc, 0, 0, 0);
    }
    #pragma unroll
    for (int reg = 0; reg < 4; ++reg)
        part[w * 272 + (lg * 4 + reg) * 17 + ln] = acc[reg];
    __syncthreads();
    {
        const int m = t >> 4, n = t & 15;   // m=co_sub, n=b16
        float sum = part[m*17+n] + part[272 + m*17+n]
                  + part[544 + m*17+n] + part[816 + m*17+n];
        atomicAdd(&s0[(size_t)(bt * 16 + n) * CO + cot * 16 + m], 0.1f * sum);
    }
}

// ---------------- routing passes 1,2 ----------------
template <int K>
__global__ __launch_bounds__(256) void route_mfma(
    const float* __restrict__ x, const float* __restrict__ W,
    const float* __restrict__ v_in, unsigned short* __restrict__ bij,
    float* __restrict__ P)
{
    __shared__ float spart[CO * 17];
    const int t  = threadIdx.x;
    const int bt = blockIdx.x & 31;
    const int sp = blockIdx.x >> 5;
    const int b0 = bt * 16;
    const int w  = t >> 6;
    const int l  = t & 63;
    const int lg = l >> 4;
    const int ln = l & 15;

    for (int i = t; i < CO * 17; i += 256) spart[i] = 0.0f;

    // v fragment: vf[tt][reg] = v[b0+ln][tt*16 + lg*4 + reg]
    f32x4 vf[CCAP];
    #pragma unroll
    for (int tt = 0; tt < CCAP; ++tt)
        vf[tt] = *reinterpret_cast<const f32x4*>(
            v_in + (size_t)(b0 + ln) * CO + tt * 16 + lg * 4);

    f32x4 sacc[CCAP];
    #pragma unroll
    for (int tt = 0; tt < CCAP; ++tt) {
        sacc[tt][0]=0.f; sacc[tt][1]=0.f; sacc[tt][2]=0.f; sacc[tt][3]=0.f;
    }

    const int rb = sp * RCHUNK + w * RWAVE;
    for (int rr = 0; rr < RWAVE; ++rr) {
        const int r = rb + rr;
        bf16x8 bfr;
        #pragma unroll
        for (int j = 0; j < 8; ++j) bfr[j] = 0;
        if (l < 16) {
            const float* xp = x + ((size_t)(b0 + l) * RR + r) * II;
            f32x4 lo = *reinterpret_cast<const f32x4*>(xp);
            f32x4 hi = *reinterpret_cast<const f32x4*>(xp + 4);
            #pragma unroll
            for (int j = 0; j < 4; ++j) { bfr[j] = f2bf(lo[j]); bfr[4+j] = f2bf(hi[j]); }
        }
        f32x4 u[CCAP];
        #pragma unroll
        for (int tt = 0; tt < CCAP; ++tt) {
            bf16x8 afr;
            #pragma unroll
            for (int j = 0; j < 8; ++j) afr[j] = 0;
            if (l < 16) {
                const float* wp = W + ((size_t)r * CO + tt * 16 + l) * II;
                f32x4 lo = *reinterpret_cast<const f32x4*>(wp);
                f32x4 hi = *reinterpret_cast<const f32x4*>(wp + 4);
                #pragma unroll
                for (int j = 0; j < 4; ++j) { afr[j] = f2bf(lo[j]); afr[4+j] = f2bf(hi[j]); }
            }
            f32x4 z; z[0]=0.f; z[1]=0.f; z[2]=0.f; z[3]=0.f;
            u[tt] = __builtin_amdgcn_mfma_f32_16x16x32_bf16(afr, bfr, z, 0, 0, 0);
        }
        // agreement a[b, c] = sum_o u*v  (o = lg*4+reg)
        float a[CCAP];
        #pragma unroll
        for (int tt = 0; tt < CCAP; ++tt) {
            float p = u[tt][0]*vf[tt][0] + u[tt][1]*vf[tt][1]
                    + u[tt][2]*vf[tt][2] + u[tt][3]*vf[tt][3];
            p += __shfl_xor(p, 16);
            p += __shfl_xor(p, 32);
            a[tt] = p;
        }
        if (K == 2) {
            #pragma unroll
            for (int tt = 0; tt < CCAP; ++tt)
                a[tt] += bf2f(bij[((size_t)r * CCAP + tt) * BB + b0 + ln]);
        } else {
            if (l < 16) {
                #pragma unroll
                for (int tt = 0; tt < CCAP; ++tt)
                    bij[((size_t)r * CCAP + tt) * BB + b0 + l] = (unsigned short)f2bf(a[tt]);
            }
        }
        // softmax over capsules (in-register, redundant across lanes)
        float m = a[0];
        #pragma unroll
        for (int tt = 1; tt < CCAP; ++tt) m = fmaxf(m, a[tt]);
        float ssum = 0.f;
        #pragma unroll
        for (int tt = 0; tt < CCAP; ++tt) { a[tt] = __expf(a[tt] - m); ssum += a[tt]; }
        float inv = 1.0f / ssum;
        #pragma unroll
        for (int tt = 0; tt < CCAP; ++tt) {
            float c = a[tt] * inv;
            sacc[tt][0] += c * u[tt][0];
            sacc[tt][1] += c * u[tt][1];
            sacc[tt][2] += c * u[tt][2];
            sacc[tt][3] += c * u[tt][3];
        }
    }
    __syncthreads();
    #pragma unroll
    for (int tt = 0; tt < CCAP; ++tt) {
        #pragma unroll
        for (int reg = 0; reg < 4; ++reg)
            atomicAdd(&spart[(tt*16 + lg*4 + reg) * 17 + ln], sacc[tt][reg]);
    }
    __syncthreads();
    float* Pu = P + (size_t)(bt * NSPLIT + sp) * 2560;
    for (int q = 0; q < 10; ++q) {
        const int idx = q * 256 + t;
        const int b16 = idx / 160, co = idx % 160;
        Pu[idx] = spart[co * 17 + b16];   // P unit layout: [b16][co]
    }
}

// ---------------- squash variants ----------------
__global__ __launch_bounds__(256) void squash_plain(
    const float* __restrict__ s, const float* __restrict__ bias,
    float* __restrict__ v_out)
{
    const int idx = blockIdx.x * 256 + threadIdx.x;   // < 81920
    const int co = idx % CO;
    float sv = s[idx] + bias[co];
    float n2 = sv * sv;
    n2 += __shfl_xor(n2, 1);
    n2 += __shfl_xor(n2, 2);
    n2 += __shfl_xor(n2, 4);
    n2 += __shfl_xor(n2, 8);
    float norm = sqrtf(n2);
    float scale = norm / (1.0f + n2 + 1e-8f);
    v_out[idx] = scale * sv;
}

__global__ __launch_bounds__(256) void squash_merge(
    const float* __restrict__ P, const float* __restrict__ bias,
    float* __restrict__ v_out)
{
    const int idx = blockIdx.x * 256 + threadIdx.x;   // < 81920
    const int b = idx / CO, co = idx % CO;
    const int bt = b >> 4, b16 = b & 15;
    const float* base = P + (size_t)bt * NSPLIT * 2560 + b16 * CO + co;
    float sv = 0.f;
    #pragma unroll
    for (int sp = 0; sp < NSPLIT; ++sp) sv += base[(size_t)sp * 2560];
    sv += bias[co];
    float n2 = sv * sv;
    n2 += __shfl_xor(n2, 1);
    n2 += __shfl_xor(n2, 2);
    n2 += __shfl_xor(n2, 4);
    n2 += __shfl_xor(n2, 8);
    float norm = sqrtf(n2);
    float scale = norm / (1.0f + n2 + 1e-8f);
    v_out[idx] = scale * sv;
}

extern "C" void kernel_launch(void* const* d_in, const int* in_sizes, int n_in,
                              void* d_out, int out_size, void* d_ws, size_t ws_size,
                              hipStream_t stream) {
    const float* x    = (const float*)d_in[0];
    const float* W    = (const float*)d_in[1];
    const float* bias = (const float*)d_in[2];
    float* out = (float*)d_out;

    float* v  = (float*)d_ws;                       // 81920
    float* s0 = v + 81920;                          // 81920
    float* P  = s0 + 81920;                         // 32*24*2560 = 1,966,080
    unsigned short* bij = (unsigned short*)(P + (size_t)NBT * NSPLIT * 2560);

    const dim3 blk(256);

    hipMemsetAsync(s0, 0, (size_t)BB * CO * sizeof(float), stream);
    gemm0<<<640, blk, 0, stream>>>(x, W, s0);
    squash_plain<<<320, blk, 0, stream>>>(s0, bias, v);

    route_mfma<1><<<NBT * NSPLIT, blk, 0, stream>>>(x, W, v, bij, P);
    squash_merge<<<320, blk, 0, stream>>>(P, bias, v);

    route_mfma<2><<<NBT * NSPLIT, blk, 0, stream>>>(x, W, v, bij, P);
    squash_merge<<<320, blk, 0, stream>>>(P, bias, out);
}

// Round 8
// 310.464 us; speedup vs baseline: 1.8998x; 1.2798x over previous
//
#include <hip/hip_runtime.h>
#include <hip/hip_bf16.h>
#include <stdint.h>

// CapsuleLayer dynamic routing via bf16 MFMA (16x16x32), unified 3-pass design.
// B=512, R=1152, C=10, O=16, I=8.
// Key insight vs R7: the MFMA A-fragment layout ((r*10+c)*16+o)*8+i is W's
// NATURAL element order, so a one-time elementwise bf16 cast of W (Wf) gives
// ready-to-load 16B/lane fragments (R7 did 32B f32 + 16 cvts per frag, per use).
// Pass K=0: c=0.1 (no agreement/softmax) -> replaces gemm0 entirely.
// D-layout (R7 HW-verified): lane l: b=l&15, co=(l>>4)*4+reg; agreement =
// 4 FMA + shfl_xor(16) + shfl_xor(32); softmax in-register.
// ws: v f32[81920] | P f32[24*32*2560] | bij bf16[1152*10*512] | Wf bf16[1474560]
//   = 22.94 MB (< 24.25 MB proven in R1).

#define BB 512
#define RR 1152
#define CCAP 10
#define II 8
#define CO 160
#define NBT 32       // b-tiles of 16
#define NSPLIT 24    // r-chunks
#define RCHUNK 48    // r per block
#define RWAVE 12     // r per wave

typedef __attribute__((ext_vector_type(8))) short bf16x8;
typedef __attribute__((ext_vector_type(4))) float f32x4;

__device__ inline short f2bf(float f) {
    uint32_t b = __float_as_uint(f);
    uint32_t r = (b + 0x7FFFu + ((b >> 16) & 1u)) >> 16;
    return (short)r;
}
__device__ inline float bf2f(unsigned short u) {
    return __uint_as_float(((uint32_t)u) << 16);
}

// ---- one-time W -> bf16 (natural order == fragment order) ----
__global__ __launch_bounds__(256) void wconv(
    const float* __restrict__ W, unsigned short* __restrict__ Wf)
{
    const int i = (blockIdx.x * 256 + threadIdx.x) * 4;  // 1,474,560 total
    f32x4 w = *reinterpret_cast<const f32x4*>(W + i);
    ushort4 o;
    o.x = (unsigned short)f2bf(w[0]); o.y = (unsigned short)f2bf(w[1]);
    o.z = (unsigned short)f2bf(w[2]); o.w = (unsigned short)f2bf(w[3]);
    *reinterpret_cast<ushort4*>(Wf + i) = o;
}

// ---- unified routing pass ----
template <int K>
__global__ __launch_bounds__(256) void route2(
    const float* __restrict__ x, const unsigned short* __restrict__ Wf,
    const float* __restrict__ v_in, unsigned short* __restrict__ bij,
    float* __restrict__ P)
{
    __shared__ float part[4 * 2720];   // [wave][co*17 + b16], 43.5 KB
    const int t  = threadIdx.x;
    const int bt = blockIdx.x & 31;
    const int sp = blockIdx.x >> 5;
    const int b0 = bt * 16;
    const int w  = t >> 6;
    const int l  = t & 63;
    const int lg = l >> 4;
    const int ln = l & 15;

    // v fragment (persistent): vf[tt][reg] = v[b0+ln][tt*16 + lg*4 + reg]
    f32x4 vf[CCAP];
    if (K > 0) {
        #pragma unroll
        for (int tt = 0; tt < CCAP; ++tt)
            vf[tt] = *reinterpret_cast<const f32x4*>(
                v_in + (size_t)(b0 + ln) * CO + tt * 16 + lg * 4);
    }

    f32x4 sacc[CCAP];
    #pragma unroll
    for (int tt = 0; tt < CCAP; ++tt) {
        sacc[tt][0]=0.f; sacc[tt][1]=0.f; sacc[tt][2]=0.f; sacc[tt][3]=0.f;
    }

    const int rb = sp * RCHUNK + w * RWAVE;
    for (int rr = 0; rr < RWAVE; ++rr) {
        const int r = rb + rr;
        // x fragment (B operand): lanes 0..15 hold k=0..7 = i; rest zero
        bf16x8 bfr;
        #pragma unroll
        for (int j = 0; j < 8; ++j) bfr[j] = 0;
        if (l < 16) {
            const float* xp = x + ((size_t)(b0 + l) * RR + r) * II;
            f32x4 lo = *reinterpret_cast<const f32x4*>(xp);
            f32x4 hi = *reinterpret_cast<const f32x4*>(xp + 4);
            #pragma unroll
            for (int j = 0; j < 4; ++j) { bfr[j] = f2bf(lo[j]); bfr[4+j] = f2bf(hi[j]); }
        }
        // u tiles: one MFMA per capsule; A-frag = direct 16B load from Wf
        f32x4 u[CCAP];
        #pragma unroll
        for (int tt = 0; tt < CCAP; ++tt) {
            bf16x8 afr;
            #pragma unroll
            for (int j = 0; j < 8; ++j) afr[j] = 0;
            if (l < 16)
                afr = *reinterpret_cast<const bf16x8*>(
                    Wf + ((size_t)r * CCAP + tt) * 128 + l * 8);
            f32x4 z; z[0]=0.f; z[1]=0.f; z[2]=0.f; z[3]=0.f;
            u[tt] = __builtin_amdgcn_mfma_f32_16x16x32_bf16(afr, bfr, z, 0, 0, 0);
        }
        if (K > 0) {
            // agreement a[b,c] = sum_o u*v  (o = lg*4+reg; xor16/32 completes)
            float a[CCAP];
            #pragma unroll
            for (int tt = 0; tt < CCAP; ++tt) {
                float p = u[tt][0]*vf[tt][0] + u[tt][1]*vf[tt][1]
                        + u[tt][2]*vf[tt][2] + u[tt][3]*vf[tt][3];
                p += __shfl_xor(p, 16);
                p += __shfl_xor(p, 32);
                a[tt] = p;
            }
            if (K == 2) {
                #pragma unroll
                for (int tt = 0; tt < CCAP; ++tt)
                    a[tt] += bf2f(bij[((size_t)r * CCAP + tt) * BB + b0 + ln]);
            } else {
                if (l < 16) {
                    #pragma unroll
                    for (int tt = 0; tt < CCAP; ++tt)
                        bij[((size_t)r * CCAP + tt) * BB + b0 + l] =
                            (unsigned short)f2bf(a[tt]);
                }
            }
            // softmax over capsules (in-register)
            float m = a[0];
            #pragma unroll
            for (int tt = 1; tt < CCAP; ++tt) m = fmaxf(m, a[tt]);
            float ssum = 0.f;
            #pragma unroll
            for (int tt = 0; tt < CCAP; ++tt) { a[tt] = __expf(a[tt] - m); ssum += a[tt]; }
            float inv = 1.0f / ssum;
            #pragma unroll
            for (int tt = 0; tt < CCAP; ++tt) {
                float c = a[tt] * inv;
                sacc[tt][0] += c * u[tt][0];
                sacc[tt][1] += c * u[tt][1];
                sacc[tt][2] += c * u[tt][2];
                sacc[tt][3] += c * u[tt][3];
            }
        } else {
            #pragma unroll
            for (int tt = 0; tt < CCAP; ++tt) {
                sacc[tt][0] += u[tt][0];
                sacc[tt][1] += u[tt][1];
                sacc[tt][2] += u[tt][2];
                sacc[tt][3] += u[tt][3];
            }
        }
    }
    if (K == 0) {
        #pragma unroll
        for (int tt = 0; tt < CCAP; ++tt) {
            sacc[tt][0] *= 0.1f; sacc[tt][1] *= 0.1f;
            sacc[tt][2] *= 0.1f; sacc[tt][3] *= 0.1f;
        }
    }
    // per-wave partials (each (b,co) owned by exactly one lane -> plain stores)
    #pragma unroll
    for (int tt = 0; tt < CCAP; ++tt) {
        #pragma unroll
        for (int reg = 0; reg < 4; ++reg)
            part[w * 2720 + (tt * 16 + lg * 4 + reg) * 17 + ln] = sacc[tt][reg];
    }
    __syncthreads();
    // merge 4 waves -> P[bt][sp] unit (layout [b16][co])
    float* Pu = P + (size_t)(bt * NSPLIT + sp) * 2560;
    for (int q = 0; q < 10; ++q) {
        const int idx = q * 256 + t;
        const int b16 = idx / 160, co = idx % 160;
        const int a0 = co * 17 + b16;
        Pu[idx] = part[a0] + part[2720 + a0] + part[5440 + a0] + part[8160 + a0];
    }
}

// ---- merge split-r partials + bias + squash ----
__global__ __launch_bounds__(256) void squash_merge(
    const float* __restrict__ P, const float* __restrict__ bias,
    float* __restrict__ v_out)
{
    const int idx = blockIdx.x * 256 + threadIdx.x;   // < 81920
    const int b = idx / CO, co = idx % CO;
    const int bt = b >> 4, b16 = b & 15;
    const float* base = P + (size_t)bt * NSPLIT * 2560 + b16 * CO + co;
    float sv = 0.f;
    #pragma unroll
    for (int sp = 0; sp < NSPLIT; ++sp) sv += base[(size_t)sp * 2560];
    sv += bias[co];
    float n2 = sv * sv;
    n2 += __shfl_xor(n2, 1);
    n2 += __shfl_xor(n2, 2);
    n2 += __shfl_xor(n2, 4);
    n2 += __shfl_xor(n2, 8);
    float norm = sqrtf(n2);
    float scale = norm / (1.0f + n2 + 1e-8f);
    v_out[idx] = scale * sv;
}

extern "C" void kernel_launch(void* const* d_in, const int* in_sizes, int n_in,
                              void* d_out, int out_size, void* d_ws, size_t ws_size,
                              hipStream_t stream) {
    const float* x    = (const float*)d_in[0];
    const float* W    = (const float*)d_in[1];
    const float* bias = (const float*)d_in[2];
    float* out = (float*)d_out;

    float* v = (float*)d_ws;                               // 81,920 f32
    float* P = v + 81920;                                  // 1,966,080 f32
    unsigned short* bij = (unsigned short*)(P + (size_t)NBT * NSPLIT * 2560); // 5,898,240 bf16
    unsigned short* Wf  = bij + (size_t)RR * CCAP * BB;    // 1,474,560 bf16

    const dim3 blk(256);
    const dim3 rgrid(NBT * NSPLIT);   // 768

    wconv<<<1440, blk, 0, stream>>>(W, Wf);

    route2<0><<<rgrid, blk, 0, stream>>>(x, Wf, v, bij, P);
    squash_merge<<<320, blk, 0, stream>>>(P, bias, v);

    route2<1><<<rgrid, blk, 0, stream>>>(x, Wf, v, bij, P);
    squash_merge<<<320, blk, 0, stream>>>(P, bias, v);

    route2<2><<<rgrid, blk, 0, stream>>>(x, Wf, v, bij, P);
    squash_merge<<<320, blk, 0, stream>>>(P, bias, out);
}